// Round 1
// baseline (23238.274 us; speedup 1.0000x reference)
//
#include <hip/hip_runtime.h>

typedef float v4f __attribute__((ext_vector_type(4)));

#define TT 512
#define BB 4096
#define BT 16
#define NTH 256

// ---- d_ws offsets (floats) ----
#define OFF_WT1 0           // [80][320]  split rows: A[256]+B[64]
#define OFF_WT2 25600       // [160][320]
#define OFF_WT3 76800
#define OFF_WT4 128000
#define OFF_WIH1 179200     // [320] split
#define OFF_BIAS 179520     // [4][320] split (b_ih+b_hh)
#define OFF_WLIN 180800     // [80]
#define OFF_BLIN 180880
#define WS_FLOATS 180881

// ---- LDS offsets (floats) ----
#define L_WBUF 0            // 2 x [32][320] weight chunk double-buffer
#define CHUNKF 10240
#define L_HT 20480          // hT[4][80][16]
#define HTL 1280
#define L_GATES 25600       // [320][16]
#define L_WIH1 30720        // [320] split
#define L_BIAS 31040        // [4][320] split
#define L_WLIN 32320        // [80]
#define L_XB 32400          // [16]
#define LDS_FLOATS 32416    // 129,664 bytes

__device__ __host__ __forceinline__ int splitg(int p) {
  // position p in split row -> original gate index g
  return (p < 256) ? ((p >> 2) * 5 + (p & 3)) : ((p - 256) * 5 + 4);
}

// ---------------- prep: transpose/pack weights into d_ws ----------------
__global__ void prep_kernel(
    const float* __restrict__ wih1, const float* __restrict__ whh1,
    const float* __restrict__ bih1, const float* __restrict__ bhh1,
    const float* __restrict__ wih2, const float* __restrict__ whh2,
    const float* __restrict__ bih2, const float* __restrict__ bhh2,
    const float* __restrict__ wih3, const float* __restrict__ whh3,
    const float* __restrict__ bih3, const float* __restrict__ bhh3,
    const float* __restrict__ wih4, const float* __restrict__ whh4,
    const float* __restrict__ bih4, const float* __restrict__ bhh4,
    const float* __restrict__ wlin, const float* __restrict__ blin,
    float* __restrict__ ws)
{
  int i = blockIdx.x * blockDim.x + threadIdx.x;
  if (i >= WS_FLOATS) return;
  if (i < OFF_WIH1) {
    int l, base;
    if (i < OFF_WT2)      { l = 0; base = OFF_WT1; }
    else if (i < OFF_WT3) { l = 1; base = OFF_WT2; }
    else if (i < OFF_WT4) { l = 2; base = OFF_WT3; }
    else                  { l = 3; base = OFF_WT4; }
    int r = i - base;
    int k = r / 320;
    int p = r - k * 320;
    int g = splitg(p);
    float v;
    if (l == 0) {
      v = whh1[g * 80 + k];                       // layer1: K=80, recurrent only
    } else {
      const float* wih = (l == 1) ? wih2 : (l == 2) ? wih3 : wih4;
      const float* whh = (l == 1) ? whh2 : (l == 2) ? whh3 : whh4;
      v = (k < 80) ? wih[g * 80 + k] : whh[g * 80 + (k - 80)];
    }
    ws[i] = v;
  } else if (i < OFF_BIAS) {
    int p = i - OFF_WIH1;
    ws[i] = wih1[splitg(p)];                      // w_ih1 is (320,1)
  } else if (i < OFF_WLIN) {
    int r = i - OFF_BIAS;
    int l = r / 320;
    int p = r - l * 320;
    int g = splitg(p);
    const float* bi_ = (l == 0) ? bih1 : (l == 1) ? bih2 : (l == 2) ? bih3 : bih4;
    const float* bh_ = (l == 0) ? bhh1 : (l == 1) ? bhh2 : (l == 2) ? bhh3 : bhh4;
    ws[i] = bi_[g] + bh_[g];
  } else if (i < OFF_BLIN) {
    ws[i] = wlin[i - OFF_WLIN];
  } else {
    ws[i] = blin[0];
  }
}

// ---------------- main persistent LSTM kernel ----------------
__device__ __forceinline__ float sigm(float x) {
  return __builtin_amdgcn_rcpf(1.f + __expf(-x));
}
__device__ __forceinline__ float tanhf_fast(float x) {
  // tanh(x) = 1 - 2/(exp(2x)+1); correct limits at +-inf
  return 1.f - 2.f * __builtin_amdgcn_rcpf(1.f + __expf(2.f * x));
}

typedef __attribute__((address_space(1))) void gvoid_t;
typedef __attribute__((address_space(3))) void svoid_t;

__device__ __forceinline__ void gload16(const float* g, float* l) {
  // async global->LDS, 16B per lane; LDS dest is wave-uniform base + lane*16
  __builtin_amdgcn_global_load_lds((gvoid_t*)g, (svoid_t*)l, 16, 0, 0);
}

__device__ __forceinline__ void fma_step(const float* hrow, const float* wrow,
                                         int tb4, int tg4, int tg,
                                         float (&accA)[4][4], float (&accB)[4]) {
  const v4f hv = *(const v4f*)(hrow + tb4);        // 4 batch values (broadcast read)
  const v4f wv = *(const v4f*)(wrow + tg4);        // 4 gate weights (aligned b128)
  const float w4 = wrow[256 + tg];                 // 5th gate weight (b32)
  #pragma unroll
  for (int bi = 0; bi < 4; ++bi) {
    const float h = hv[bi];
    #pragma unroll
    for (int gi = 0; gi < 4; ++gi) accA[bi][gi] = fmaf(h, wv[gi], accA[bi][gi]);
    accB[bi] = fmaf(h, w4, accB[bi]);
  }
}

__global__ void __launch_bounds__(NTH, 1)
lstm_main(const float* __restrict__ input, const float* __restrict__ ws,
          float* __restrict__ out)
{
  extern __shared__ __align__(16) float sm[];
  const int tid = threadIdx.x;
  const int lane = tid & 63;
  const int wave = tid >> 6;
  const int b0 = blockIdx.x * BT;
  const int tb4 = (tid & 3) * 4;    // this thread's 4 batch rows: tb4..tb4+3
  const int tg = tid >> 2;          // gate-group 0..63 (5 gates each)
  const int tg4 = tg * 4;
  const int jb = tid & 15;          // activation: batch index
  const int j0 = tid >> 4;          // activation: hidden base (j = j0+16i)

  // ---- init ----
  for (int i = tid; i < 4 * 80 * 16; i += NTH) sm[L_HT + i] = 0.f;
  for (int i = tid; i < 1680; i += NTH) sm[L_WIH1 + i] = ws[OFF_WIH1 + i];
  if (tid < BT) sm[L_XB + tid] = input[(b0 + tid) * TT];
  {
    const float* src = ws + OFF_WT1;          // layer1 chunk 0 -> buf 0
    float* dst = sm + L_WBUF;
    for (int i = wave; i < 40; i += 4)
      gload16(src + i * 256 + lane * 4, dst + i * 256);
  }
  __syncthreads();

  float creg[4][5];
  #pragma unroll
  for (int l = 0; l < 4; ++l) {
    #pragma unroll
    for (int i = 0; i < 5; ++i) creg[l][i] = 0.f;
  }

  const float blin = ws[OFF_BLIN];
  int cur = 0;
  float xreg = 0.f;

  for (int t = 0; t < TT; ++t) {
    #pragma unroll
    for (int l = 0; l < 4; ++l) {
      const int K = (l == 0) ? 80 : 160;
      const int nc = (K + 31) >> 5;

      // ---- accumulator init: bias (+ x*w_ih1 for layer 1) ----
      float accA[4][4];
      float accB[4];
      {
        const v4f bA = *(const v4f*)&sm[L_BIAS + l * 320 + tg4];
        const float bB = sm[L_BIAS + l * 320 + 256 + tg];
        #pragma unroll
        for (int bi = 0; bi < 4; ++bi) {
          #pragma unroll
          for (int gi = 0; gi < 4; ++gi) accA[bi][gi] = bA[gi];
          accB[bi] = bB;
        }
        if (l == 0) {
          const v4f wiA = *(const v4f*)&sm[L_WIH1 + tg4];
          const float wiB = sm[L_WIH1 + 256 + tg];
          #pragma unroll
          for (int bi = 0; bi < 4; ++bi) {
            const float xv = sm[L_XB + tb4 + bi];
            #pragma unroll
            for (int gi = 0; gi < 4; ++gi)
              accA[bi][gi] = fmaf(xv, wiA[gi], accA[bi][gi]);
            accB[bi] = fmaf(xv, wiB, accB[bi]);
          }
        }
      }
      // prefetch next step's x into a register (consumed at layer-4 activation)
      if (l == 0 && tid < BT) {
        const int tn = (t + 1 < TT) ? (t + 1) : t;
        xreg = input[(b0 + tid) * TT + tn];
      }

      const int slotA = (l == 0) ? 0 : (l - 1);  // x-source hT slot (k<80)
      const int slotB = l;                       // recurrent hT slot (k>=80)

      #pragma unroll 1
      for (int c = 0; c < nc; ++c) {
        // ---- stage NEXT chunk into the other buffer (async) ----
        {
          int nl, ncc;
          if (c + 1 < nc)      { nl = l;     ncc = c + 1; }
          else if (l < 3)      { nl = l + 1; ncc = 0; }
          else                 { nl = 0;     ncc = 0; }    // next step's layer1
          const int woff = (nl == 0) ? OFF_WT1 : (nl == 1) ? OFF_WT2
                         : (nl == 2) ? OFF_WT3 : OFF_WT4;
          const int Kn = (nl == 0) ? 80 : 160;
          const int rows = min(32, Kn - ncc * 32);
          const int ninst = (rows * 1280) >> 10;           // 1KB per wave-inst
          const float* src = ws + woff + ncc * CHUNKF;
          float* dst = sm + L_WBUF + (cur ^ 1) * CHUNKF;
          for (int i = wave; i < ninst; i += 4)
            gload16(src + i * 256 + lane * 4, dst + i * 256);
        }
        // ---- compute current chunk ----
        const float* wb = sm + L_WBUF + cur * CHUNKF;
        const int k0 = c * 32;
        const int rows = min(32, K - k0);
        const int xr = min(max(80 - k0, 0), rows);   // rows from x-source
        const float* hA = sm + L_HT + slotA * HTL;
        const float* hB = sm + L_HT + slotB * HTL;
        #pragma unroll 4
        for (int kk = 0; kk < xr; ++kk)
          fma_step(hA + (k0 + kk) * 16, wb + kk * 320, tb4, tg4, tg, accA, accB);
        #pragma unroll 4
        for (int kk = xr; kk < rows; ++kk)
          fma_step(hB + (k0 + kk - 80) * 16, wb + kk * 320, tb4, tg4, tg, accA, accB);

        if (c == nc - 1) {  // write gates (original-g indexed, [g][16b])
          #pragma unroll
          for (int gi = 0; gi < 4; ++gi) {
            v4f v = {accA[0][gi], accA[1][gi], accA[2][gi], accA[3][gi]};
            *(v4f*)&sm[L_GATES + (tg * 5 + gi) * 16 + tb4] = v;
          }
          v4f v = {accB[0], accB[1], accB[2], accB[3]};
          *(v4f*)&sm[L_GATES + (tg * 5 + 4) * 16 + tb4] = v;
        }
        __syncthreads();
        cur ^= 1;
      }

      // ---- activation: c in registers, h -> LDS (transposed [j][16b]) ----
      #pragma unroll
      for (int i = 0; i < 5; ++i) {
        const int j = j0 + 16 * i;
        const float g_i = sm[L_GATES + j * 16 + jb];
        const float g_f = sm[L_GATES + (80 + j) * 16 + jb];
        const float g_g = sm[L_GATES + (160 + j) * 16 + jb];
        const float g_o = sm[L_GATES + (240 + j) * 16 + jb];
        const float cn = sigm(g_f) * creg[l][i] + sigm(g_i) * tanhf_fast(g_g);
        creg[l][i] = cn;
        sm[L_HT + l * HTL + j * 16 + jb] = sigm(g_o) * tanhf_fast(cn);
      }
      if (l == 3 && tid < BT) sm[L_XB + tid] = xreg;  // publish next step's x
      __syncthreads();

      // ---- output = h2 @ w_lin + b_lin (wave 0 only; layer index l==1) ----
      if (l == 1 && tid < 64) {
        const int ob = tid >> 2, kp = tid & 3;
        const float* h2 = sm + L_HT + 1 * HTL;
        float p = 0.f;
        #pragma unroll
        for (int k = 0; k < 20; ++k)
          p = fmaf(h2[(kp * 20 + k) * 16 + ob], sm[L_WLIN + kp * 20 + k], p);
        p += __shfl_xor(p, 1);
        p += __shfl_xor(p, 2);
        if (kp == 0) out[(b0 + ob) * TT + t] = p + blin;
      }
    }
  }
}

// ---------------- host launcher ----------------
extern "C" void kernel_launch(void* const* d_in, const int* in_sizes, int n_in,
                              void* d_out, int out_size, void* d_ws, size_t ws_size,
                              hipStream_t stream) {
  const float* input = (const float*)d_in[0];
  const float* wih1 = (const float*)d_in[1];
  const float* whh1 = (const float*)d_in[2];
  const float* bih1 = (const float*)d_in[3];
  const float* bhh1 = (const float*)d_in[4];
  const float* wih2 = (const float*)d_in[5];
  const float* whh2 = (const float*)d_in[6];
  const float* bih2 = (const float*)d_in[7];
  const float* bhh2 = (const float*)d_in[8];
  const float* wih3 = (const float*)d_in[9];
  const float* whh3 = (const float*)d_in[10];
  const float* bih3 = (const float*)d_in[11];
  const float* bhh3 = (const float*)d_in[12];
  const float* wih4 = (const float*)d_in[13];
  const float* whh4 = (const float*)d_in[14];
  const float* bih4 = (const float*)d_in[15];
  const float* bhh4 = (const float*)d_in[16];
  const float* wlin = (const float*)d_in[17];
  const float* blin = (const float*)d_in[18];
  float* ws = (float*)d_ws;
  float* out = (float*)d_out;

  hipLaunchKernelGGL(prep_kernel, dim3((WS_FLOATS + 255) / 256), dim3(256), 0,
                     stream,
                     wih1, whh1, bih1, bhh1, wih2, whh2, bih2, bhh2,
                     wih3, whh3, bih3, bhh3, wih4, whh4, bih4, bhh4,
                     wlin, blin, ws);

  hipFuncSetAttribute(reinterpret_cast<const void*>(lstm_main),
                      hipFuncAttributeMaxDynamicSharedMemorySize,
                      LDS_FLOATS * 4);
  hipLaunchKernelGGL(lstm_main, dim3(BB / BT), dim3(NTH), LDS_FLOATS * 4, stream,
                     input, ws, out);
}

// Round 5
// 17633.562 us; speedup vs baseline: 1.3178x; 1.3178x over previous
//
#include <hip/hip_runtime.h>

typedef float v4f __attribute__((ext_vector_type(4)));
typedef _Float16 h8 __attribute__((ext_vector_type(8)));

#define TT 512
#define BB 4096
#define BT 16
#define NTH 256
#define ARS 328              // A row stride in fp16 (80*4 cols + pad -> 656 B rows, 16B aligned)
#define NHB 36               // half-steps per time-step (18 k-steps x {hi,lo})
#define HBB 20480            // bytes per half-step block (20 tiles x 64 lanes x 16 B)
#define STREAM_BYTES (NHB * HBB)   // 737,280 B in d_ws

// ---------------- prep: pack weights as fp16 hi/lo B-fragment stream ----------------
// stream element order: [halfstep hb][tile T 0..19][lane L 0..63][j 0..7] fp16
// k-step map: ks 0..17 -> layer l (3,5,5,5 steps), hb = 2*ks (+1 for lo)
// B value at (n = 16T + (L&15), k = 32s + (L>>4)*8 + j), window-relative k:
//   l==0: k<80 -> whh1[n][k], else 0 (zero-padded tail rows)
//   l>=1: k<80 -> wih_l[n][k] (x-source = h_{l-1}), else whh_l[n][k-80]
__global__ void prep_pack(const float* __restrict__ whh1,
                          const float* __restrict__ wih2, const float* __restrict__ whh2,
                          const float* __restrict__ wih3, const float* __restrict__ whh3,
                          const float* __restrict__ wih4, const float* __restrict__ whh4,
                          _Float16* __restrict__ stream)
{
  int e = blockIdx.x * blockDim.x + threadIdx.x;
  if (e >= NHB * (HBB / 2)) return;
  int hb = e / (HBB / 2);
  int r  = e - hb * (HBB / 2);
  int T  = r >> 9;
  int r2 = r & 511;
  int L  = r2 >> 3;
  int j  = r2 & 7;
  int ks = hb >> 1;
  int is_lo = hb & 1;
  int l = (ks < 3) ? 0 : (ks < 8) ? 1 : (ks < 13) ? 2 : 3;
  int s = ks - ((l == 0) ? 0 : (l == 1) ? 3 : (l == 2) ? 8 : 13);
  int n = 16 * T + (L & 15);
  int k = 32 * s + ((L >> 4) << 3) + j;
  float w;
  if (l == 0) {
    w = (k < 80) ? whh1[n * 80 + k] : 0.f;
  } else {
    const float* wih = (l == 1) ? wih2 : (l == 2) ? wih3 : wih4;
    const float* whh = (l == 1) ? whh2 : (l == 2) ? whh3 : whh4;
    w = (k < 80) ? wih[n * 80 + k] : whh[n * 80 + (k - 80)];
  }
  _Float16 hi = (_Float16)w;
  _Float16 v = is_lo ? (_Float16)((w - (float)hi) * 4096.f) : hi;
  stream[e] = v;
}

// ---------------- main persistent LSTM kernel ----------------
__device__ __forceinline__ float sigm(float x) {
  return __builtin_amdgcn_rcpf(1.f + __expf(-x));
}
__device__ __forceinline__ float tanh_fast(float x) {
  return 1.f - 2.f * __builtin_amdgcn_rcpf(1.f + __expf(2.f * x));
}
// barrier WITHOUT vmcnt drain: keeps prefetched global loads in flight
__device__ __forceinline__ void bar() {
  asm volatile("s_waitcnt lgkmcnt(0)" ::: "memory");
  __builtin_amdgcn_s_barrier();
  asm volatile("" ::: "memory");
}

__global__ void __launch_bounds__(NTH, 1)
lstm_main(const float* __restrict__ input,
          const _Float16* __restrict__ stream,
          const float* __restrict__ bih1, const float* __restrict__ bhh1,
          const float* __restrict__ bih2, const float* __restrict__ bhh2,
          const float* __restrict__ bih3, const float* __restrict__ bhh3,
          const float* __restrict__ bih4, const float* __restrict__ bhh4,
          const float* __restrict__ wih1, const float* __restrict__ wlin,
          const float* __restrict__ blin, float* __restrict__ out)
{
  __shared__ __align__(16) float s_gates[320 * 20];      // [n][16 batch + pad4]
  __shared__ __align__(16) _Float16 s_Ahi[16 * ARS];     // A rows = batch, cols = h1|h2|h3|h4
  __shared__ __align__(16) _Float16 s_Alo[16 * ARS];     // (h - hi) * 4096
  __shared__ __align__(16) float s_h2[80 * 16];          // f32 h2 for w_lin dot
  __shared__ __align__(16) float s_bias[4 * 320];
  __shared__ __align__(16) float s_wih1[320];
  __shared__ __align__(16) float s_wlin[80];
  __shared__ __align__(16) float s_xb[16];

  const int tid  = threadIdx.x;
  const int lane = tid & 63;
  const int wv   = tid >> 6;
  const int b0   = blockIdx.x * BT;
  const int m15  = lane & 15;
  const int quad = lane >> 4;
  const int mb   = quad * 4;       // C rows (batches) mb..mb+3
  const int jb   = tid & 15;       // activation: batch
  const int j0   = tid >> 4;       // activation: hidden base

  // ---- init ----
  for (int i = tid; i < 320; i += NTH) {
    s_bias[i]       = bih1[i] + bhh1[i];
    s_bias[320 + i] = bih2[i] + bhh2[i];
    s_bias[640 + i] = bih3[i] + bhh3[i];
    s_bias[960 + i] = bih4[i] + bhh4[i];
    s_wih1[i] = wih1[i];
  }
  for (int i = tid; i < 80; i += NTH) s_wlin[i] = wlin[i];
  for (int i = tid; i < 16 * ARS / 2; i += NTH) {
    ((unsigned*)s_Ahi)[i] = 0u;
    ((unsigned*)s_Alo)[i] = 0u;
  }
  if (tid < 16) s_xb[tid] = input[(b0 + tid) * TT];
  const float blinv = blin[0];

  // ---- B-fragment register ring (4 half-steps x 5 tiles x 16 B) ----
  v4f bf[4][5];
  const char* sbase = (const char*)stream + wv * 5120 + lane * 16;
#define ISSUE(H) do { const char* p_ = sbase + (H) * HBB;      \
    bf[(H) & 3][0] = *(const v4f*)(p_);                        \
    bf[(H) & 3][1] = *(const v4f*)(p_ + 1024);                 \
    bf[(H) & 3][2] = *(const v4f*)(p_ + 2048);                 \
    bf[(H) & 3][3] = *(const v4f*)(p_ + 3072);                 \
    bf[(H) & 3][4] = *(const v4f*)(p_ + 4096); } while (0)

  ISSUE(0); ISSUE(1); ISSUE(2);   // prologue prefetch (depth 3)

  float creg[4][5];
#pragma unroll
  for (int l = 0; l < 4; ++l)
#pragma unroll
    for (int i = 0; i < 5; ++i) creg[l][i] = 0.f;

  float xreg = 0.f;
  bar();

  for (int t = 0; t < TT; ++t) {
#pragma unroll
    for (int l = 0; l < 4; ++l) {
      const int NSL = (l == 0) ? 3 : 5;
      const int KBL = (l == 0) ? 0 : (l == 1) ? 3 : (l == 2) ? 8 : 13;
      const int CBL = (l == 0) ? 0 : 80 * (l - 1);   // A window start col

      // ---- accumulator init: bias (+ x*w_ih1 for layer 1) ----
      v4f acch[5], accl[5];
#pragma unroll
      for (int tl = 0; tl < 5; ++tl) {
        const int n = 16 * (5 * wv + tl) + m15;
        const float b = s_bias[l * 320 + n];
        v4f a;
        if (l == 0) {
          const float wi = s_wih1[n];
#pragma unroll
          for (int r = 0; r < 4; ++r) a[r] = b + s_xb[mb + r] * wi;
        } else {
#pragma unroll
          for (int r = 0; r < 4; ++r) a[r] = b;
        }
        acch[tl] = a;
        accl[tl] = (v4f){0.f, 0.f, 0.f, 0.f};
      }

      // ---- MFMA K loop (software-pipelined A-frags, ring-prefetched B) ----
      const int ab0 = m15 * ARS + CBL + quad * 8;
      h8 ahi = *(const h8*)&s_Ahi[ab0];
      h8 alo = *(const h8*)&s_Alo[ab0];
#pragma unroll
      for (int s = 0; s < NSL; ++s) {
        const int q = 2 * (KBL + s);         // hi half-step index
        ISSUE((q + 3) % NHB);
        h8 anh, anl;
        if (s + 1 < NSL) {
          anh = *(const h8*)&s_Ahi[ab0 + 32 * (s + 1)];
          anl = *(const h8*)&s_Alo[ab0 + 32 * (s + 1)];
        }
#pragma unroll
        for (int tl = 0; tl < 5; ++tl)
          acch[tl] = __builtin_amdgcn_mfma_f32_16x16x32_f16(
              ahi, __builtin_bit_cast(h8, bf[q & 3][tl]), acch[tl], 0, 0, 0);
#pragma unroll
        for (int tl = 0; tl < 5; ++tl)
          accl[tl] = __builtin_amdgcn_mfma_f32_16x16x32_f16(
              alo, __builtin_bit_cast(h8, bf[q & 3][tl]), accl[tl], 0, 0, 0);
        ISSUE((q + 4) % NHB);
#pragma unroll
        for (int tl = 0; tl < 5; ++tl)
          accl[tl] = __builtin_amdgcn_mfma_f32_16x16x32_f16(
              ahi, __builtin_bit_cast(h8, bf[(q + 1) & 3][tl]), accl[tl], 0, 0, 0);
        if (s + 1 < NSL) { ahi = anh; alo = anl; }
      }

      // ---- C write: gates[n][m] ----
#pragma unroll
      for (int tl = 0; tl < 5; ++tl) {
        const int n = 16 * (5 * wv + tl) + m15;
        v4f o = acch[tl] + accl[tl] * 0.000244140625f;   // + lo-acc * 2^-12
        *(v4f*)&s_gates[n * 20 + mb] = o;
      }
      bar();

      // ---- activation: c in regs, h -> fp16 hi/lo A-fragments ----
#pragma unroll
      for (int i = 0; i < 5; ++i) {
        const int j = j0 + 16 * i;
        const float gi = s_gates[j * 20 + jb];
        const float gf = s_gates[(80 + j) * 20 + jb];
        const float gg = s_gates[(160 + j) * 20 + jb];
        const float go = s_gates[(240 + j) * 20 + jb];
        const float cn = sigm(gf) * creg[l][i] + sigm(gi) * tanh_fast(gg);
        creg[l][i] = cn;
        const float h = sigm(go) * tanh_fast(cn);
        const _Float16 hh = (_Float16)h;
        s_Ahi[jb * ARS + 80 * l + j] = hh;
        s_Alo[jb * ARS + 80 * l + j] = (_Float16)((h - (float)hh) * 4096.f);
        if (l == 1) s_h2[j * 16 + jb] = h;
      }
      if (l == 0 && tid < 16)
        xreg = input[(b0 + tid) * TT + ((t + 1 < TT) ? (t + 1) : t)];
      if (l == 3 && tid < 16) s_xb[tid] = xreg;
      bar();

      // ---- output = h2 @ w_lin + b_lin ----
      if (l == 1 && tid < 64) {
        const int ob = tid >> 2, kp = tid & 3;
        float p = 0.f;
#pragma unroll
        for (int k = 0; k < 20; ++k)
          p = fmaf(s_h2[(kp * 20 + k) * 16 + ob], s_wlin[kp * 20 + k], p);
        p += __shfl_xor(p, 1);
        p += __shfl_xor(p, 2);
        if (kp == 0) out[(b0 + ob) * TT + t] = p + blinv;
      }
    }
  }
#undef ISSUE
}

// ---------------- host launcher ----------------
extern "C" void kernel_launch(void* const* d_in, const int* in_sizes, int n_in,
                              void* d_out, int out_size, void* d_ws, size_t ws_size,
                              hipStream_t stream) {
  const float* input = (const float*)d_in[0];
  const float* wih1 = (const float*)d_in[1];
  const float* whh1 = (const float*)d_in[2];
  const float* bih1 = (const float*)d_in[3];
  const float* bhh1 = (const float*)d_in[4];
  const float* wih2 = (const float*)d_in[5];
  const float* whh2 = (const float*)d_in[6];
  const float* bih2 = (const float*)d_in[7];
  const float* bhh2 = (const float*)d_in[8];
  const float* wih3 = (const float*)d_in[9];
  const float* whh3 = (const float*)d_in[10];
  const float* bih3 = (const float*)d_in[11];
  const float* bhh3 = (const float*)d_in[12];
  const float* wih4 = (const float*)d_in[13];
  const float* whh4 = (const float*)d_in[14];
  const float* bih4 = (const float*)d_in[15];
  const float* bhh4 = (const float*)d_in[16];
  const float* wlin = (const float*)d_in[17];
  const float* blin = (const float*)d_in[18];
  _Float16* ws = (_Float16*)d_ws;
  float* out = (float*)d_out;

  hipLaunchKernelGGL(prep_pack, dim3((NHB * (HBB / 2) + 255) / 256), dim3(256), 0,
                     stream, whh1, wih2, whh2, wih3, whh3, wih4, whh4, ws);

  hipLaunchKernelGGL(lstm_main, dim3(BB / BT), dim3(NTH), 0, stream,
                     input, ws,
                     bih1, bhh1, bih2, bhh2, bih3, bhh3, bih4, bhh4,
                     wih1, wlin, blin, out);
}